// Round 12
// baseline (140.599 us; speedup 1.0000x reference)
//
#include <hip/hip_runtime.h>
#include <hip/hip_bf16.h>

using bf16x8 = __attribute__((ext_vector_type(8))) short;
using f32x4  = __attribute__((ext_vector_type(4))) float;

#define SEQ      2048
#define DMODEL   1024
#define NHEADS   16
#define HDIM     64
#define MROWS    4096   // BATCH*SEQ

__device__ __forceinline__ unsigned short f2bf(float f) {
  union { float f; unsigned u; } c; c.f = f;
  unsigned r = c.u + 0x7FFFu + ((c.u >> 16) & 1u);
  return (unsigned short)(r >> 16);
}

__device__ __forceinline__ void gload16(const void* g, void* s) {
  __builtin_amdgcn_global_load_lds(
      (const __attribute__((address_space(1))) void*)g,
      (__attribute__((address_space(3))) void*)s, 16, 0, 0);
}

// ---------------- zero-fill (graph-capture-safe memset) ----------------------
__global__ void zero_f4(float4* __restrict__ p, int n4) {
  int i = blockIdx.x * blockDim.x + threadIdx.x;
  if (i < n4) p[i] = make_float4(0.f, 0.f, 0.f, 0.f);
}

// ---------------- fp32 -> bf16 conversion, all 5 tensors in one launch -------
__global__ void cvt_all(const float* __restrict__ x,  const float* __restrict__ wq,
                        const float* __restrict__ wk, const float* __restrict__ wv,
                        const float* __restrict__ wo,
                        unsigned short* __restrict__ xb,  unsigned short* __restrict__ wqb,
                        unsigned short* __restrict__ wkb, unsigned short* __restrict__ wvb,
                        unsigned short* __restrict__ wob)
{
  int i = blockIdx.x * blockDim.x + threadIdx.x;   // 0 .. 2097151 float4s
  const float* src; unsigned short* dst; int off;
  if (i < 1048576) { src = x; dst = xb; off = i; }
  else {
    int k = i - 1048576, seg = k >> 18; off = k & 262143;
    if      (seg == 0) { src = wq; dst = wqb; }
    else if (seg == 1) { src = wk; dst = wkb; }
    else if (seg == 2) { src = wv; dst = wvb; }
    else               { src = wo; dst = wob; }
  }
  const float4 v = ((const float4*)src)[off];
  ushort4 o;
  o.x = f2bf(v.x); o.y = f2bf(v.y); o.z = f2bf(v.z); o.w = f2bf(v.w);
  ((ushort4*)dst)[off] = o;
}

// ---------------- fused QKV projection GEMM ---------------------------------
// grid 768 = 3/CU; launch_bounds(256,3) guarantees all 3 co-resident
// (m97-class kernel ~164 VGPR fits the 170 cap).
__global__ __launch_bounds__(256, 3)
void gemm_qkv(const unsigned short* __restrict__ Ab,
              const unsigned short* __restrict__ Wqb,
              const unsigned short* __restrict__ Wkb,
              const unsigned short* __restrict__ Wvb,
              const float* __restrict__ bq, const float* __restrict__ bk,
              const float* __restrict__ bv,
              unsigned short* __restrict__ Qo, unsigned short* __restrict__ Ko,
              unsigned short* __restrict__ Vto)
{
  __shared__ unsigned short As[128 * 64];
  __shared__ unsigned short Bs[128 * 64];
  const int t  = threadIdx.x;
  const int w  = t >> 6, l = t & 63;
  const int lr = l & 15, lg = l >> 4;
  const int bm = blockIdx.x / 24;
  const int bn = blockIdx.x % 24;
  const int which = bn >> 3;
  const unsigned short* Bsrc = which == 0 ? Wqb : (which == 1 ? Wkb : Wvb);
  const float* biasp = which == 0 ? bq : (which == 1 ? bk : bv);
  const int bnw = bn & 7;
  const int wm = w >> 1, wn = w & 1;

  const char* Agp = (const char*)Ab + (size_t)bm * 128 * 2048;
  const char* Bgp = (const char*)Bsrc + (size_t)bnw * 128 * 2048;

  f32x4 acc[4][4];
  #pragma unroll
  for (int a = 0; a < 4; ++a)
    #pragma unroll
    for (int b = 0; b < 4; ++b) acc[a][b] = (f32x4){0.f, 0.f, 0.f, 0.f};

  for (int kt = 0; kt < 16; ++kt) {
    const int kbyte = kt * 128;
    #pragma unroll
    for (int i = 0; i < 4; ++i) {
      int idx  = i * 256 + t;
      int row  = idx >> 3;
      int colb = (idx & 7) << 4;
      gload16(Agp + (size_t)row * 2048 + kbyte + colb, (char*)As + idx * 16);
      gload16(Bgp + (size_t)row * 2048 + kbyte + colb, (char*)Bs + idx * 16);
    }
    __syncthreads();
    #pragma unroll
    for (int kk = 0; kk < 2; ++kk) {
      bf16x8 af[4], bfr[4];
      #pragma unroll
      for (int x = 0; x < 4; ++x) {
        af[x]  = *(const bf16x8*)&As[(wm * 64 + x * 16 + lr) * 64 + kk * 32 + lg * 8];
        bfr[x] = *(const bf16x8*)&Bs[(wn * 64 + x * 16 + lr) * 64 + kk * 32 + lg * 8];
      }
      #pragma unroll
      for (int xa = 0; xa < 4; ++xa)
        #pragma unroll
        for (int xb = 0; xb < 4; ++xb)
          acc[xa][xb] = __builtin_amdgcn_mfma_f32_16x16x32_bf16(af[xa], bfr[xb], acc[xa][xb], 0, 0, 0);
    }
    __syncthreads();
  }

  #pragma unroll
  for (int xb = 0; xb < 4; ++xb) {
    int colg = bnw * 128 + wn * 64 + xb * 16 + lr;
    int h  = colg >> 6, dh = colg & 63;
    float biasv = biasp[colg];
    #pragma unroll
    for (int xa = 0; xa < 4; ++xa) {
      int row0 = bm * 128 + wm * 64 + xa * 16 + lg * 4;
      #pragma unroll
      for (int i = 0; i < 4; ++i) {
        int m = row0 + i;
        int b = m >> 11, s = m & 2047;
        unsigned short u = f2bf(acc[xa][xb][i] + biasv);
        if (which == 0)
          Qo[(((size_t)(b * NHEADS + h)) * SEQ + s) * HDIM + dh] = u;
        else if (which == 1)
          Ko[(((size_t)(b * NHEADS + h)) * SEQ + s) * HDIM + dh] = u;
        else
          Vto[(((size_t)(b * NHEADS + h)) * HDIM + dh) * SEQ + s] = u;
      }
    }
  }
}

// ---------------- causal flash attention helpers -----------------------------
__device__ __forceinline__ void stage_kv64(const char* Kg, const char* Vg,
                                           char* Kl, char* Vl, int nb, int t)
{
  #pragma unroll
  for (int i = 0; i < 2; ++i) {
    int idx = i * 256 + t;
    int row = idx >> 3, colb = (idx & 7) << 4;
    int scol = colb ^ ((row & 7) << 4);
    gload16(Kg + (size_t)(nb + row) * 128 + scol, Kl + idx * 16);
    gload16(Vg + (size_t)row * 4096 + (size_t)nb * 2 + scol, Vl + idx * 16);
  }
}

// One 64-key subtile for a 16-row wave: S = QK^T, mask, P = exp2(S*c) via LDS,
// O += P@V, L += P@1.  All register arrays statically indexed (rule #20).
__device__ __forceinline__ void attn_sub16(const char* Kl, const char* Vl, char* Pw,
                                           const bf16x8 (&qf)[2], const bf16x8 ones,
                                           f32x4 (&o)[4], f32x4 &accL,
                                           int q0w, int kbase, bool diag, int lr, int lg)
{
  bf16x8 kf[4][2];
  #pragma unroll
  for (int n = 0; n < 4; ++n)
    #pragma unroll
    for (int kk = 0; kk < 2; ++kk)
      kf[n][kk] = *(const bf16x8*)(Kl + (size_t)(n * 16 + lr) * 128 +
                                   ((kk * 64 + lg * 16) ^ ((lr & 7) << 4)));
  f32x4 s[4];
  __builtin_amdgcn_s_setprio(1);
  #pragma unroll
  for (int n = 0; n < 4; ++n) {
    f32x4 acc = (f32x4){0.f, 0.f, 0.f, 0.f};
    #pragma unroll
    for (int kk = 0; kk < 2; ++kk)
      acc = __builtin_amdgcn_mfma_f32_16x16x32_bf16(qf[kk], kf[n][kk], acc, 0, 0, 0);
    s[n] = acc;
  }
  __builtin_amdgcn_s_setprio(0);
  if (diag) {
    #pragma unroll
    for (int n = 0; n < 4; ++n) {
      int key = kbase + n * 16 + lr;
      #pragma unroll
      for (int i = 0; i < 4; ++i) {
        int query = q0w + lg * 4 + i;
        if (key > query) s[n][i] = -3.0e38f;
      }
    }
  }
  #pragma unroll
  for (int n = 0; n < 4; ++n)
    #pragma unroll
    for (int i = 0; i < 4; ++i) {
      float p = exp2f(s[n][i] * 0.180336881f);   // 0.125 * log2(e)
      union { float fl; unsigned u; } cv; cv.fl = p;
      int prow = lg * 4 + i;
      int pcb  = ((n * 16 + lr) * 2) ^ ((prow & 7) << 4);
      *(unsigned short*)(Pw + prow * 128 + pcb) =
          (unsigned short)((cv.u + 0x8000u) >> 16);
    }
  __builtin_amdgcn_s_setprio(1);
  #pragma unroll
  for (int kk = 0; kk < 2; ++kk) {
    bf16x8 af = *(const bf16x8*)(Pw + lr * 128 + ((kk * 64 + lg * 16) ^ ((lr & 7) << 4)));
    accL = __builtin_amdgcn_mfma_f32_16x16x32_bf16(af, ones, accL, 0, 0, 0);
    #pragma unroll
    for (int n = 0; n < 4; ++n) {
      bf16x8 vf = *(const bf16x8*)(Vl + (size_t)(n * 16 + lr) * 128 +
                    ((kk * 64 + lg * 16) ^ ((lr & 7) << 4)));
      o[n] = __builtin_amdgcn_mfma_f32_16x16x32_bf16(af, vf, o[n], 0, 0, 0);
    }
  }
  __builtin_amdgcn_s_setprio(0);
}

// ---------------- causal flash attention, key-chunked ------------------------
// Fixed-shift softmax is LINEAR over keys (no running max) -> a q-tile's key
// range splits across blocks; partials combine by addition. Work item =
// (bh, qt, chunk of <=8 trips): 80 chunks/bh -> grid 2560 = j*32+bh.
// Max block duration = 8 trips (was 32 -> R11's makespan problem); ~10
// blocks/CU with refill keeps 4 resident (LDS 40 KB) the whole kernel.
// qt<=7 (s<512, single chunk): normalize + write bf16 Attn directly.
// qt>=8: atomicAdd fp32 partial O into O32 and row-sum into L32; attn_norm
// finishes. blockIdx%8 = bh%8 -> all chunks of one bh share an XCD (K/V L2).
__global__ __launch_bounds__(256, 4)
void attn_fwd(const unsigned short* __restrict__ Q,
              const unsigned short* __restrict__ K,
              const unsigned short* __restrict__ Vt,
              unsigned short* __restrict__ O,
              float* __restrict__ O32, float* __restrict__ L32)
{
  const int t = threadIdx.x;
  const int w = t >> 6, l = t & 63;
  const int lr = l & 15, lg = l >> 4;
  const int bh = blockIdx.x & 31;
  const int j  = blockIdx.x >> 5;              // 0..79
  int qt, c0;
  if (j < 8)       { qt = j;                  c0 = 0; }
  else if (j < 24) { qt = 8 + ((j - 8) >> 1); c0 = (j - 8) & 1; }
  else if (j < 48) { qt = 16 + (j - 24) / 3;  c0 = (j - 24) % 3; }
  else             { qt = 24 + ((j - 48) >> 2); c0 = (j - 48) & 3; }
  const int nc  = 1 + (qt >> 3);
  const int kb0 = c0 * 8;
  const int kbe = (kb0 + 8 < qt + 1) ? (kb0 + 8) : (qt + 1);
  const int b = bh >> 4, h = bh & 15;
  const int q0w = qt * 64 + w * 16;

  const unsigned short* Qp = Q + (size_t)bh * SEQ * HDIM;
  const char* Kg = (const char*)(K  + (size_t)bh * SEQ * HDIM);
  const char* Vg = (const char*)(Vt + (size_t)bh * HDIM * SEQ);

  __shared__ unsigned short Klds[2][64 * 64];    // 16 KB [key][dh] swizzled
  __shared__ unsigned short Vlds[2][64 * 64];    // 16 KB [dh][key] swizzled
  __shared__ unsigned short Plds[4][16][64];     //  8 KB per-wave P, swizzled
  char* Pw = (char*)Plds[w];

  bf16x8 qf[2];
  #pragma unroll
  for (int kk = 0; kk < 2; ++kk)
    qf[kk] = *(const bf16x8*)(Qp + (size_t)(q0w + lr) * HDIM + kk * 32 + lg * 8);

  bf16x8 ones;
  #pragma unroll
  for (int e = 0; e < 8; ++e) ones[e] = (short)0x3F80;   // bf16 1.0

  f32x4 o[4];
  f32x4 accL = (f32x4){0.f, 0.f, 0.f, 0.f};
  #pragma unroll
  for (int n = 0; n < 4; ++n) o[n] = (f32x4){0.f, 0.f, 0.f, 0.f};

  stage_kv64(Kg, Vg, (char*)Klds[0], (char*)Vlds[0], kb0 * 64, t);
  __syncthreads();
  int cur = 0;
  for (int kb = kb0; kb < kbe; ++kb) {
    if (kb + 1 < kbe)
      stage_kv64(Kg, Vg, (char*)Klds[cur ^ 1], (char*)Vlds[cur ^ 1], (kb + 1) * 64, t);
    attn_sub16((const char*)Klds[cur], (const char*)Vlds[cur], Pw, qf, ones,
               o, accL, q0w, kb * 64, kb == qt, lr, lg);
    __syncthreads();
    cur ^= 1;
  }

  if (nc == 1) {
    // single chunk: full (O,L) in-block -> normalize + bf16 write
    #pragma unroll
    for (int n = 0; n < 4; ++n) {
      int col = h * HDIM + n * 16 + lr;
      #pragma unroll
      for (int i = 0; i < 4; ++i) {
        int srow = q0w + lg * 4 + i;
        O[((size_t)(b * SEQ + srow)) * DMODEL + col] = f2bf(o[n][i] / accL[i]);
      }
    }
  } else {
    // partial: accumulate fp32 (linear combine across chunks)
    #pragma unroll
    for (int i = 0; i < 4; ++i) {
      int row = b * SEQ + q0w + lg * 4 + i;
      #pragma unroll
      for (int n = 0; n < 4; ++n)
        atomicAdd(&O32[(size_t)row * DMODEL + h * HDIM + n * 16 + lr], o[n][i]);
      if (lr == 0) atomicAdd(&L32[row * NHEADS + h], accL[i]);
    }
  }
}

// ---------------- attn partial normalize (rows s >= 512) ---------------------
__global__ void attn_norm(const float* __restrict__ O32, const float* __restrict__ L32,
                          unsigned short* __restrict__ Attn)
{
  int i = blockIdx.x * blockDim.x + threadIdx.x;   // 3072 rows * 256 f4-cols
  int col4 = i & 255;
  int rr = i >> 8;                                 // 0..3071
  int b = rr / 1536, s = 512 + (rr % 1536);
  int row = b * SEQ + s;
  float4 ov = ((const float4*)O32)[(size_t)row * 256 + col4];
  float lv = L32[row * NHEADS + (col4 >> 4)];
  float inv = 1.0f / lv;
  ushort4 u;
  u.x = f2bf(ov.x * inv); u.y = f2bf(ov.y * inv);
  u.z = f2bf(ov.z * inv); u.w = f2bf(ov.w * inv);
  ((ushort4*)Attn)[(size_t)row * 256 + col4] = u;
}

// ---------------- output projection GEMM (fp32 out + bias, 128x64 tiles) ----
// 512 blocks = 2/CU (was 256 = 1/CU -> 1 wave/SIMD latency-exposed).
__global__ __launch_bounds__(256, 2)
void gemm_out(const unsigned short* __restrict__ Ab, const unsigned short* __restrict__ Bb,
              const float* __restrict__ bias, float* __restrict__ C)
{
  __shared__ unsigned short As[128 * 64];   // 16 KB
  __shared__ unsigned short Bs[64 * 64];    //  8 KB
  const int t  = threadIdx.x;
  const int w  = t >> 6, l = t & 63;
  const int lr = l & 15, lg = l >> 4;
  const int bm = blockIdx.x >> 4;           // 32
  const int bn = blockIdx.x & 15;           // 16
  const int wm = w >> 1, wn = w & 1;

  const char* Agp = (const char*)Ab + (size_t)bm * 128 * 2048;
  const char* Bgp = (const char*)Bb + (size_t)bn * 64 * 2048;

  f32x4 acc[4][2];
  #pragma unroll
  for (int a = 0; a < 4; ++a)
    #pragma unroll
    for (int b = 0; b < 2; ++b) acc[a][b] = (f32x4){0.f, 0.f, 0.f, 0.f};

  for (int kt = 0; kt < 16; ++kt) {
    const int kbyte = kt * 128;
    #pragma unroll
    for (int i = 0; i < 4; ++i) {
      int idx  = i * 256 + t;
      int row  = idx >> 3;
      int colb = (idx & 7) << 4;
      gload16(Agp + (size_t)row * 2048 + kbyte + colb, (char*)As + idx * 16);
    }
    #pragma unroll
    for (int i = 0; i < 2; ++i) {
      int idx  = i * 256 + t;
      int row  = idx >> 3;
      int colb = (idx & 7) << 4;
      gload16(Bgp + (size_t)row * 2048 + kbyte + colb, (char*)Bs + idx * 16);
    }
    __syncthreads();
    #pragma unroll
    for (int kk = 0; kk < 2; ++kk) {
      bf16x8 af[4], bfr[2];
      #pragma unroll
      for (int x = 0; x < 4; ++x)
        af[x]  = *(const bf16x8*)&As[(wm * 64 + x * 16 + lr) * 64 + kk * 32 + lg * 8];
      #pragma unroll
      for (int x = 0; x < 2; ++x)
        bfr[x] = *(const bf16x8*)&Bs[(wn * 32 + x * 16 + lr) * 64 + kk * 32 + lg * 8];
      #pragma unroll
      for (int xa = 0; xa < 4; ++xa)
        #pragma unroll
        for (int xb = 0; xb < 2; ++xb)
          acc[xa][xb] = __builtin_amdgcn_mfma_f32_16x16x32_bf16(af[xa], bfr[xb], acc[xa][xb], 0, 0, 0);
    }
    __syncthreads();
  }
  #pragma unroll
  for (int xb = 0; xb < 2; ++xb) {
    int col = bn * 64 + wn * 32 + xb * 16 + lr;
    float bvv = bias[col];
    #pragma unroll
    for (int xa = 0; xa < 4; ++xa) {
      int row0 = bm * 128 + wm * 64 + xa * 16 + lg * 4;
      #pragma unroll
      for (int i = 0; i < 4; ++i)
        C[(size_t)(row0 + i) * DMODEL + col] = acc[xa][xb][i] + bvv;
    }
  }
}

// ---------------- launcher ---------------------------------------------------
extern "C" void kernel_launch(void* const* d_in, const int* in_sizes, int n_in,
                              void* d_out, int out_size, void* d_ws, size_t ws_size,
                              hipStream_t stream)
{
  const float* x  = (const float*)d_in[0];
  // d_in[1] is the causal mask — constant tril, applied analytically in attn_fwd.
  const float* Wq = (const float*)d_in[2];
  const float* bq = (const float*)d_in[3];
  const float* Wk = (const float*)d_in[4];
  const float* bk = (const float*)d_in[5];
  const float* Wv = (const float*)d_in[6];
  const float* bv = (const float*)d_in[7];
  const float* Wo = (const float*)d_in[8];
  const float* bo = (const float*)d_in[9];

  char* ws = (char*)d_ws;
  const size_t MB = 1024 * 1024;
  unsigned short* xb   = (unsigned short*)(ws + 0);        // 8 MB (dead after qkv)
  unsigned short* Wqb  = (unsigned short*)(ws + 8  * MB);  // 2 MB (dead after qkv)
  unsigned short* Wkb  = (unsigned short*)(ws + 10 * MB);  // 2 MB (dead after qkv)
  unsigned short* Wvb  = (unsigned short*)(ws + 12 * MB);  // 2 MB (dead after qkv)
  // 14..16 MB: tail of O32
  unsigned short* Qb   = (unsigned short*)(ws + 16 * MB);  // 8 MB
  unsigned short* Kb   = (unsigned short*)(ws + 24 * MB);  // 8 MB
  unsigned short* Vtb  = (unsigned short*)(ws + 32 * MB);  // 8 MB
  unsigned short* Attn = (unsigned short*)(ws + 40 * MB);  // 8 MB
  unsigned short* Wob  = (unsigned short*)(ws + 48 * MB);  // 2 MB
  float*          L32  = (float*)(ws + 50 * MB);           // 256 KB
  float*          O32  = (float*)(ws + 0);                 // 16 MB, aliases xb..Wvb

  cvt_all<<<8192, 256, 0, stream>>>(x, Wq, Wk, Wv, Wo, xb, Wqb, Wkb, Wvb, Wob);
  gemm_qkv<<<768, 256, 0, stream>>>(xb, Wqb, Wkb, Wvb, bq, bk, bv, Qb, Kb, Vtb);
  zero_f4<<<4096, 256, 0, stream>>>((float4*)O32, 1048576);   // 16 MB
  zero_f4<<<64,   256, 0, stream>>>((float4*)L32, 16384);     // 256 KB
  attn_fwd<<<2560, 256, 0, stream>>>(Qb, Kb, Vtb, Attn, O32, L32);
  attn_norm<<<3072, 256, 0, stream>>>(O32, L32, Attn);
  gemm_out<<<512, 256, 0, stream>>>(Attn, Wob, bo, (float*)d_out);
}

// Round 13
// 113.364 us; speedup vs baseline: 1.2402x; 1.2402x over previous
//
#include <hip/hip_runtime.h>
#include <hip/hip_bf16.h>

using bf16x8 = __attribute__((ext_vector_type(8))) short;
using f32x4  = __attribute__((ext_vector_type(4))) float;

#define SEQ      2048
#define DMODEL   1024
#define NHEADS   16
#define HDIM     64
#define MROWS    4096   // BATCH*SEQ

__device__ __forceinline__ unsigned short f2bf(float f) {
  union { float f; unsigned u; } c; c.f = f;
  unsigned r = c.u + 0x7FFFu + ((c.u >> 16) & 1u);
  return (unsigned short)(r >> 16);
}

// pack 2 floats -> 2 bf16 in one u32 (low = a, high = b); m240: no builtin.
__device__ __forceinline__ unsigned cvtpk(float a, float b) {
  unsigned r;
  asm("v_cvt_pk_bf16_f32 %0, %1, %2" : "=v"(r) : "v"(a), "v"(b));
  return r;
}

__device__ __forceinline__ void gload16(const void* g, void* s) {
  __builtin_amdgcn_global_load_lds(
      (const __attribute__((address_space(1))) void*)g,
      (__attribute__((address_space(3))) void*)s, 16, 0, 0);
}

// ---------------- fp32 -> bf16 conversion, all 5 tensors in one launch -------
__global__ void cvt_all(const float* __restrict__ x,  const float* __restrict__ wq,
                        const float* __restrict__ wk, const float* __restrict__ wv,
                        const float* __restrict__ wo,
                        unsigned short* __restrict__ xb,  unsigned short* __restrict__ wqb,
                        unsigned short* __restrict__ wkb, unsigned short* __restrict__ wvb,
                        unsigned short* __restrict__ wob)
{
  int i = blockIdx.x * blockDim.x + threadIdx.x;   // 0 .. 2097151 float4s
  const float* src; unsigned short* dst; int off;
  if (i < 1048576) { src = x; dst = xb; off = i; }
  else {
    int k = i - 1048576, seg = k >> 18; off = k & 262143;
    if      (seg == 0) { src = wq; dst = wqb; }
    else if (seg == 1) { src = wk; dst = wkb; }
    else if (seg == 2) { src = wv; dst = wvb; }
    else               { src = wo; dst = wob; }
  }
  const float4 v = ((const float4*)src)[off];
  ushort4 o;
  o.x = f2bf(v.x); o.y = f2bf(v.y); o.z = f2bf(v.z); o.w = f2bf(v.w);
  ((ushort4*)dst)[off] = o;
}

// ---------------- fused QKV projection GEMM ---------------------------------
// Q rows are PRE-SCALED by 0.125*log2(e) so attn's softmax needs no per-
// element multiply (p = exp2(S') directly).
__global__ __launch_bounds__(256, 2)
void gemm_qkv(const unsigned short* __restrict__ Ab,
              const unsigned short* __restrict__ Wqb,
              const unsigned short* __restrict__ Wkb,
              const unsigned short* __restrict__ Wvb,
              const float* __restrict__ bq, const float* __restrict__ bk,
              const float* __restrict__ bv,
              unsigned short* __restrict__ Qo, unsigned short* __restrict__ Ko,
              unsigned short* __restrict__ Vto)
{
  __shared__ unsigned short As[128 * 64];
  __shared__ unsigned short Bs[128 * 64];
  const int t  = threadIdx.x;
  const int w  = t >> 6, l = t & 63;
  const int lr = l & 15, lg = l >> 4;
  const int bm = blockIdx.x / 24;
  const int bn = blockIdx.x % 24;
  const int which = bn >> 3;
  const unsigned short* Bsrc = which == 0 ? Wqb : (which == 1 ? Wkb : Wvb);
  const float* biasp = which == 0 ? bq : (which == 1 ? bk : bv);
  const int bnw = bn & 7;
  const int wm = w >> 1, wn = w & 1;

  const char* Agp = (const char*)Ab + (size_t)bm * 128 * 2048;
  const char* Bgp = (const char*)Bsrc + (size_t)bnw * 128 * 2048;

  f32x4 acc[4][4];
  #pragma unroll
  for (int a = 0; a < 4; ++a)
    #pragma unroll
    for (int b = 0; b < 4; ++b) acc[a][b] = (f32x4){0.f, 0.f, 0.f, 0.f};

  for (int kt = 0; kt < 16; ++kt) {
    const int kbyte = kt * 128;
    #pragma unroll
    for (int i = 0; i < 4; ++i) {
      int idx  = i * 256 + t;
      int row  = idx >> 3;
      int colb = (idx & 7) << 4;
      gload16(Agp + (size_t)row * 2048 + kbyte + colb, (char*)As + idx * 16);
      gload16(Bgp + (size_t)row * 2048 + kbyte + colb, (char*)Bs + idx * 16);
    }
    __syncthreads();
    #pragma unroll
    for (int kk = 0; kk < 2; ++kk) {
      bf16x8 af[4], bfr[4];
      #pragma unroll
      for (int x = 0; x < 4; ++x) {
        af[x]  = *(const bf16x8*)&As[(wm * 64 + x * 16 + lr) * 64 + kk * 32 + lg * 8];
        bfr[x] = *(const bf16x8*)&Bs[(wn * 64 + x * 16 + lr) * 64 + kk * 32 + lg * 8];
      }
      #pragma unroll
      for (int xa = 0; xa < 4; ++xa)
        #pragma unroll
        for (int xb = 0; xb < 4; ++xb)
          acc[xa][xb] = __builtin_amdgcn_mfma_f32_16x16x32_bf16(af[xa], bfr[xb], acc[xa][xb], 0, 0, 0);
    }
    __syncthreads();
  }

  #pragma unroll
  for (int xb = 0; xb < 4; ++xb) {
    int colg = bnw * 128 + wn * 64 + xb * 16 + lr;
    int h  = colg >> 6, dh = colg & 63;
    float biasv = biasp[colg];
    #pragma unroll
    for (int xa = 0; xa < 4; ++xa) {
      int row0 = bm * 128 + wm * 64 + xa * 16 + lg * 4;
      #pragma unroll
      for (int i = 0; i < 4; ++i) {
        int m = row0 + i;
        int b = m >> 11, s = m & 2047;
        float v = acc[xa][xb][i] + biasv;
        if (which == 0) {
          Qo[(((size_t)(b * NHEADS + h)) * SEQ + s) * HDIM + dh] = f2bf(v * 0.180336881f);
        } else if (which == 1) {
          Ko[(((size_t)(b * NHEADS + h)) * SEQ + s) * HDIM + dh] = f2bf(v);
        } else {
          Vto[(((size_t)(b * NHEADS + h)) * HDIM + dh) * SEQ + s] = f2bf(v);
        }
      }
    }
  }
}

// ---------------- causal flash attention helpers -----------------------------
// 256-thread staging of a 64-key tile: K 64x64 bf16 (8 KB) + V^T 64x64 (8 KB),
// 2 x 16B chunks per thread each, XOR-swizzled via pre-swizzled global source.
__device__ __forceinline__ void stage_kv64(const char* Kg, const char* Vg,
                                           char* Kl, char* Vl, int nb, int t)
{
  #pragma unroll
  for (int i = 0; i < 2; ++i) {
    int idx = i * 256 + t;
    int row = idx >> 3, colb = (idx & 7) << 4;
    int scol = colb ^ ((row & 7) << 4);
    gload16(Kg + (size_t)(nb + row) * 128 + scol, Kl + idx * 16);
    gload16(Vg + (size_t)row * 4096 + (size_t)nb * 2 + scol, Vl + idx * 16);
  }
}

// One 64-key subtile, SWAPPED QK^T (same fragments, transposed C): lane(lg,lr)
// holds S^T for q = q0w+lr, keys kbase + n*16 + lg*4 + i -> 4 CONSECUTIVE keys
// per (n) -> cvt_pk pairs + one ds_write_b64 per n (was 16 ds_write_b16 + 32
// bit-ops; R12 lesson: kernel is VALU/LDS-issue-bound in the P pipeline).
// Q is pre-scaled so p = exp2(s) with no multiply. PV side unchanged.
__device__ __forceinline__ void attn_sub16(const char* Kl, const char* Vl, char* Pw,
                                           const bf16x8 (&qf)[2], const bf16x8 ones,
                                           f32x4 (&o)[4], f32x4 &accL,
                                           int q0w, int kbase, bool diag, int lr, int lg)
{
  bf16x8 kf[4][2];
  #pragma unroll
  for (int n = 0; n < 4; ++n)
    #pragma unroll
    for (int kk = 0; kk < 2; ++kk)
      kf[n][kk] = *(const bf16x8*)(Kl + (size_t)(n * 16 + lr) * 128 +
                                   ((kk * 64 + lg * 16) ^ ((lr & 7) << 4)));
  f32x4 st[4];
  __builtin_amdgcn_s_setprio(1);
  #pragma unroll
  for (int n = 0; n < 4; ++n) {
    f32x4 acc = (f32x4){0.f, 0.f, 0.f, 0.f};
    #pragma unroll
    for (int kk = 0; kk < 2; ++kk)
      acc = __builtin_amdgcn_mfma_f32_16x16x32_bf16(kf[n][kk], qf[kk], acc, 0, 0, 0);
    st[n] = acc;
  }
  __builtin_amdgcn_s_setprio(0);
  if (diag) {                    // causal mask: key > q -> -inf
    #pragma unroll
    for (int n = 0; n < 4; ++n) {
      #pragma unroll
      for (int i = 0; i < 4; ++i) {
        int key = kbase + n * 16 + lg * 4 + i;
        if (key > q0w + lr) st[n][i] = -3.0e38f;
      }
    }
  }
  // exp2 + pack pairs + 8B write into P[q=lr][key], swizzled (2-way banks)
  #pragma unroll
  for (int n = 0; n < 4; ++n) {
    float p0 = exp2f(st[n][0]);
    float p1 = exp2f(st[n][1]);
    float p2 = exp2f(st[n][2]);
    float p3 = exp2f(st[n][3]);
    uint2 pw;
    pw.x = cvtpk(p0, p1);
    pw.y = cvtpk(p2, p3);
    *(uint2*)(Pw + lr * 128 + ((n * 32 + lg * 8) ^ ((lr & 7) << 4))) = pw;
  }
  __builtin_amdgcn_s_setprio(1);
  #pragma unroll
  for (int kk = 0; kk < 2; ++kk) {
    bf16x8 af = *(const bf16x8*)(Pw + lr * 128 + ((kk * 64 + lg * 16) ^ ((lr & 7) << 4)));
    accL = __builtin_amdgcn_mfma_f32_16x16x32_bf16(af, ones, accL, 0, 0, 0);
    #pragma unroll
    for (int n = 0; n < 4; ++n) {
      bf16x8 vf = *(const bf16x8*)(Vl + (size_t)(n * 16 + lr) * 128 +
                    ((kk * 64 + lg * 16) ^ ((lr & 7) << 4)));
      o[n] = __builtin_amdgcn_mfma_f32_16x16x32_bf16(af, vf, o[n], 0, 0, 0);
    }
  }
  __builtin_amdgcn_s_setprio(0);
}

// ---------------- causal flash attention -------------------------------------
// grid = 1024 = 32 qt-slots * 32 bh; 256 thr = 4 waves * 16 q-rows.
// Co-resident blocks {s, s+8, s+16, s+24} (same bh) -> qt {s,15-s,16+s,31-s}:
// groups sum to 66 trips (R11 balance). LDS 40 KB -> 4 blocks/CU.
__global__ __launch_bounds__(256, 4)
void attn_fwd(const unsigned short* __restrict__ Q,
              const unsigned short* __restrict__ K,
              const unsigned short* __restrict__ Vt,
              unsigned short* __restrict__ O)
{
  const int t = threadIdx.x;
  const int w = t >> 6, l = t & 63;
  const int lr = l & 15, lg = l >> 4;
  const int bh   = blockIdx.x & 31;
  const int slot = blockIdx.x >> 5;            // 0..31
  const int qt   = (slot < 8)  ? slot
                 : (slot < 16) ? (23 - slot)
                 : (slot < 24) ? slot
                 :               (55 - slot);
  const int b = bh >> 4, h = bh & 15;
  const int q0w = qt * 64 + w * 16;

  const unsigned short* Qp = Q + (size_t)bh * SEQ * HDIM;
  const char* Kg = (const char*)(K  + (size_t)bh * SEQ * HDIM);
  const char* Vg = (const char*)(Vt + (size_t)bh * HDIM * SEQ);

  __shared__ unsigned short Klds[2][64 * 64];    // 16 KB [key][dh] swizzled
  __shared__ unsigned short Vlds[2][64 * 64];    // 16 KB [dh][key] swizzled
  __shared__ unsigned short Plds[4][16][64];     //  8 KB per-wave P, swizzled
  char* Pw = (char*)Plds[w];

  bf16x8 qf[2];
  #pragma unroll
  for (int kk = 0; kk < 2; ++kk)
    qf[kk] = *(const bf16x8*)(Qp + (size_t)(q0w + lr) * HDIM + kk * 32 + lg * 8);

  bf16x8 ones;
  #pragma unroll
  for (int e = 0; e < 8; ++e) ones[e] = (short)0x3F80;   // bf16 1.0

  f32x4 o[4];
  f32x4 accL = (f32x4){0.f, 0.f, 0.f, 0.f};
  #pragma unroll
  for (int n = 0; n < 4; ++n) o[n] = (f32x4){0.f, 0.f, 0.f, 0.f};

  const int trips = qt + 1;   // 64-key subtiles; all 4 waves run all trips

  stage_kv64(Kg, Vg, (char*)Klds[0], (char*)Vlds[0], 0, t);
  __syncthreads();
  int cur = 0;
  for (int kb = 0; kb < trips; ++kb) {
    if (kb + 1 < trips)
      stage_kv64(Kg, Vg, (char*)Klds[cur ^ 1], (char*)Vlds[cur ^ 1], (kb + 1) * 64, t);
    attn_sub16((const char*)Klds[cur], (const char*)Vlds[cur], Pw, qf, ones,
               o, accL, q0w, kb * 64, kb == trips - 1, lr, lg);
    __syncthreads();
    cur ^= 1;
  }

  // epilogue: normalize by L, write attn[(b*S+s)][h*64+dh]
  // (o,accL C layout: q-row = q0w + lg*4 + i, dh col = n*16 + lr)
  #pragma unroll
  for (int n = 0; n < 4; ++n) {
    int col = h * HDIM + n * 16 + lr;
    #pragma unroll
    for (int i = 0; i < 4; ++i) {
      int srow = q0w + lg * 4 + i;
      O[((size_t)(b * SEQ + srow)) * DMODEL + col] = f2bf(o[n][i] / accL[i]);
    }
  }
}

// ---------------- output projection GEMM (fp32 out + bias, 128x64 tiles) ----
// 512 blocks = 2/CU (256 = 1/CU left every latency exposed).
__global__ __launch_bounds__(256, 2)
void gemm_out(const unsigned short* __restrict__ Ab, const unsigned short* __restrict__ Bb,
              const float* __restrict__ bias, float* __restrict__ C)
{
  __shared__ unsigned short As[128 * 64];   // 16 KB
  __shared__ unsigned short Bs[64 * 64];    //  8 KB
  const int t  = threadIdx.x;
  const int w  = t >> 6, l = t & 63;
  const int lr = l & 15, lg = l >> 4;
  const int bm = blockIdx.x >> 4;           // 32
  const int bn = blockIdx.x & 15;           // 16
  const int wm = w >> 1, wn = w & 1;

  const char* Agp = (const char*)Ab + (size_t)bm * 128 * 2048;
  const char* Bgp = (const char*)Bb + (size_t)bn * 64 * 2048;

  f32x4 acc[4][2];
  #pragma unroll
  for (int a = 0; a < 4; ++a)
    #pragma unroll
    for (int b = 0; b < 2; ++b) acc[a][b] = (f32x4){0.f, 0.f, 0.f, 0.f};

  for (int kt = 0; kt < 16; ++kt) {
    const int kbyte = kt * 128;
    #pragma unroll
    for (int i = 0; i < 4; ++i) {
      int idx  = i * 256 + t;
      int row  = idx >> 3;
      int colb = (idx & 7) << 4;
      gload16(Agp + (size_t)row * 2048 + kbyte + colb, (char*)As + idx * 16);
    }
    #pragma unroll
    for (int i = 0; i < 2; ++i) {
      int idx  = i * 256 + t;
      int row  = idx >> 3;
      int colb = (idx & 7) << 4;
      gload16(Bgp + (size_t)row * 2048 + kbyte + colb, (char*)Bs + idx * 16);
    }
    __syncthreads();
    #pragma unroll
    for (int kk = 0; kk < 2; ++kk) {
      bf16x8 af[4], bfr[2];
      #pragma unroll
      for (int x = 0; x < 4; ++x)
        af[x]  = *(const bf16x8*)&As[(wm * 64 + x * 16 + lr) * 64 + kk * 32 + lg * 8];
      #pragma unroll
      for (int x = 0; x < 2; ++x)
        bfr[x] = *(const bf16x8*)&Bs[(wn * 32 + x * 16 + lr) * 64 + kk * 32 + lg * 8];
      #pragma unroll
      for (int xa = 0; xa < 4; ++xa)
        #pragma unroll
        for (int xb = 0; xb < 2; ++xb)
          acc[xa][xb] = __builtin_amdgcn_mfma_f32_16x16x32_bf16(af[xa], bfr[xb], acc[xa][xb], 0, 0, 0);
    }
    __syncthreads();
  }
  #pragma unroll
  for (int xb = 0; xb < 2; ++xb) {
    int col = bn * 64 + wn * 32 + xb * 16 + lr;
    float bvv = bias[col];
    #pragma unroll
    for (int xa = 0; xa < 4; ++xa) {
      int row0 = bm * 128 + wm * 64 + xa * 16 + lg * 4;
      #pragma unroll
      for (int i = 0; i < 4; ++i)
        C[(size_t)(row0 + i) * DMODEL + col] = acc[xa][xb][i] + bvv;
    }
  }
}

// ---------------- launcher ---------------------------------------------------
extern "C" void kernel_launch(void* const* d_in, const int* in_sizes, int n_in,
                              void* d_out, int out_size, void* d_ws, size_t ws_size,
                              hipStream_t stream)
{
  const float* x  = (const float*)d_in[0];
  // d_in[1] is the causal mask — constant tril, applied analytically in attn_fwd.
  const float* Wq = (const float*)d_in[2];
  const float* bq = (const float*)d_in[3];
  const float* Wk = (const float*)d_in[4];
  const float* bk = (const float*)d_in[5];
  const float* Wv = (const float*)d_in[6];
  const float* bv = (const float*)d_in[7];
  const float* Wo = (const float*)d_in[8];
  const float* bo = (const float*)d_in[9];

  char* ws = (char*)d_ws;
  const size_t MB = 1024 * 1024;
  unsigned short* xb   = (unsigned short*)(ws + 0);        // 8 MB  [4096][1024]
  unsigned short* Wqb  = (unsigned short*)(ws + 8  * MB);  // 2 MB
  unsigned short* Wkb  = (unsigned short*)(ws + 10 * MB);  // 2 MB
  unsigned short* Wvb  = (unsigned short*)(ws + 12 * MB);  // 2 MB
  unsigned short* Wob  = (unsigned short*)(ws + 14 * MB);  // 2 MB
  unsigned short* Qb   = (unsigned short*)(ws + 16 * MB);  // 8 MB  [(bh)*S+s][dh] (pre-scaled)
  unsigned short* Kb   = (unsigned short*)(ws + 24 * MB);  // 8 MB  [(bh)*S+s][dh]
  unsigned short* Vtb  = (unsigned short*)(ws + 32 * MB);  // 8 MB  [(bh)*64+dh][s]
  unsigned short* Attn = (unsigned short*)(ws + 40 * MB);  // 8 MB  [b*S+s][dmodel]

  cvt_all<<<8192, 256, 0, stream>>>(x, Wq, Wk, Wv, Wo, xb, Wqb, Wkb, Wvb, Wob);
  gemm_qkv<<<768, 256, 0, stream>>>(xb, Wqb, Wkb, Wvb, bq, bk, bv, Qb, Kb, Vtb);
  attn_fwd<<<1024, 256, 0, stream>>>(Qb, Kb, Vtb, Attn);
  gemm_out<<<512, 256, 0, stream>>>(Attn, Wob, bo, (float*)d_out);
}